// Round 5
// baseline (234.957 us; speedup 1.0000x reference)
//
#include <hip/hip_runtime.h>

typedef __attribute__((ext_vector_type(8))) short short8;
typedef __attribute__((ext_vector_type(16))) float float16;

#define NPIX_HID 8388608   // 8*64*128*128

__device__ __forceinline__ short f2bf(float f) {
    union { float f; unsigned u; } v; v.f = f;
    unsigned r = (v.u + 0x7FFFu + ((v.u >> 16) & 1u)) >> 16;
    return (short)r;
}

__device__ __forceinline__ float sigmoidf_(float v) { return 1.f / (1.f + __expf(-v)); }
__device__ __forceinline__ float tanhf_(float v)    { return 2.f / (1.f + __expf(-2.f * v)) - 1.f; }

// Pack W -> Aprep[kk][cig][t][r][j], r = gate*8+cl, phys co = gate*64 + t*8 + cl.
// A-frag for 32x32x16: lane m=lane&31 reads 8 ci at cig=(kc*4+ks*2+h); offset linear in kt.
__global__ void wprep(const float* __restrict__ W, short* __restrict__ A) {
    int tid = blockIdx.x * 256 + threadIdx.x;
    if (tid >= 9 * 16 * 8 * 32 * 8) return;
    int j   = tid & 7;
    int r   = (tid >> 3) & 31;
    int t   = (tid >> 8) & 7;
    int cig = (tid >> 11) & 15;
    int kk  = tid >> 15;
    int g = r >> 3, cl = r & 7;
    int co = g * 64 + t * 8 + cl;
    int ci = cig * 8 + j;
    A[tid] = f2bf(W[co * 1152 + ci * 9 + kk]);
}

__global__ __launch_bounds__(256, 2) void convlstm_main(
    const float* __restrict__ x, const float* __restrict__ ph,
    const float* __restrict__ pc, const short* __restrict__ aprep,
    const float* __restrict__ bg, float* __restrict__ out)
{
    // Swizzled: 16B unit index off16 = (row*66+px)*16 + (cig ^ (px&15));  67584 B
    __shared__ short Bs[4 * 66 * 128];

    const int tid  = threadIdx.x;
    const int lane = tid & 63;
    const int wave = tid >> 6;
    const int l31  = lane & 31;
    const int h    = lane >> 5;
    const int mhalf = wave & 1;      // co half: channels mhalf*32..+31
    const int nhalf = wave >> 1;     // y-row within the 2-row block

    const int t  = blockIdx.x;       // 1024 blocks
    const int x0 = (t & 1) * 64;
    const int y0 = ((t >> 1) & 63) * 2;
    const int b  = t >> 7;

    // ---- stage 4 halo rows x 66 px x 128 ci, fp32->bf16, swizzled b128 stores ----
    for (int i = tid; i < 4224; i += 256) {
        const int px  = i % 66;
        const int ro  = i / 66;
        const int oct = ro & 15;
        const int row = ro >> 4;
        const int ysrc = y0 + row - 1;
        const int xsrc = x0 + px - 1;
        short8 pk = {0,0,0,0,0,0,0,0};
        if ((unsigned)ysrc < 128u && (unsigned)xsrc < 128u) {
            const float* src = (oct < 8) ? x : ph;
            const float* sp = src + (((b * 64 + (oct & 7) * 8) * 128 + ysrc) * 128 + xsrc);
#pragma unroll
            for (int j = 0; j < 8; ++j) pk[j] = f2bf(sp[j * 16384]);
        }
        const int off16 = (row * 66 + px) * 16 + (oct ^ (px & 15));
        *(short8*)&Bs[off16 * 8] = pk;
    }
    __syncthreads();

    float16 acc[4][2];
#pragma unroll
    for (int mt = 0; mt < 4; ++mt)
#pragma unroll
        for (int nt = 0; nt < 2; ++nt)
#pragma unroll
            for (int e = 0; e < 16; ++e) acc[mt][nt][e] = 0.f;

    // A pointers: + h*2048 + l31*8 + mhalf*1024 shorts; per kt advance +8192 shorts
    const short* ap0 = aprep + h * 2048 + l31 * 8 + mhalf * 1024;
    const short* ap1 = ap0 + 4096;   // ks=1

    short8 abuf[2][2][4];            // [parity][ks][mt]
#pragma unroll
    for (int ks = 0; ks < 2; ++ks)
#pragma unroll
        for (int mt = 0; mt < 4; ++mt)
            abuf[0][ks][mt] = *(const short8*)((ks ? ap1 : ap0) + mt * 256);

    const int lB = l31;              // px in-lane part

#define HALF_BODY(KT, P, ADV)                                                      \
    {                                                                              \
        const int kt  = (KT);                                                      \
        const int kkk = kt >> 2, kc = kt & 3;                                      \
        const int ky  = (kkk * 11) >> 5;                                           \
        const int kx  = kkk - ky * 3;                                              \
        if (ADV) { ap0 += 8192; ap1 += 8192;                                       \
            _Pragma("unroll")                                                      \
            for (int ks = 0; ks < 2; ++ks)                                         \
                _Pragma("unroll")                                                  \
                for (int mt = 0; mt < 4; ++mt)                                     \
                    abuf[(P) ^ 1][ks][mt] =                                        \
                        *(const short8*)((ks ? ap1 : ap0) + mt * 256);             \
        }                                                                          \
        const int pxb = kx + lB;                                                   \
        const int q   = pxb & 15;                                                  \
        const int rh  = ky + nhalf;                                                \
        short8 bfr[2][2];                                                          \
        _Pragma("unroll")                                                          \
        for (int ks = 0; ks < 2; ++ks) {                                           \
            const int gx = ((kc * 4 + ks * 2) | h) ^ q;                            \
            _Pragma("unroll")                                                      \
            for (int nt = 0; nt < 2; ++nt) {                                       \
                const int off16 = (rh * 66 + nt * 32 + pxb) * 16 + gx;             \
                bfr[ks][nt] = *(const short8*)&Bs[off16 * 8];                      \
            }                                                                      \
        }                                                                          \
        _Pragma("unroll")                                                          \
        for (int mt = 0; mt < 4; ++mt)                                             \
            _Pragma("unroll")                                                      \
            for (int nt = 0; nt < 2; ++nt) {                                       \
                acc[mt][nt] = __builtin_amdgcn_mfma_f32_32x32x16_bf16(             \
                    abuf[P][0][mt], bfr[0][nt], acc[mt][nt], 0, 0, 0);             \
                acc[mt][nt] = __builtin_amdgcn_mfma_f32_32x32x16_bf16(             \
                    abuf[P][1][mt], bfr[1][nt], acc[mt][nt], 0, 0, 0);             \
            }                                                                      \
    }

#pragma unroll 1
    for (int it = 0; it < 18; ++it) {
        const int kt0 = it * 2;
        HALF_BODY(kt0, 0, 1)
        HALF_BODY(kt0 + 1, 1, (it < 17))
    }
#undef HALF_BODY

    // ---- fused gating epilogue: lane holds 4 channels x 4 gates per (mt,nt) ----
    const int yy = y0 + nhalf;
#pragma unroll
    for (int mt = 0; mt < 4; ++mt) {
        const int c0 = (mhalf * 4 + mt) * 8 + 4 * h;
#pragma unroll
        for (int nt = 0; nt < 2; ++nt) {
            const int px = x0 + nt * 32 + l31;
#pragma unroll
            for (int a = 0; a < 4; ++a) {
                const int c = c0 + a;
                const float gi = acc[mt][nt][a]      + bg[c];
                const float gf = acc[mt][nt][4 + a]  + bg[64 + c];
                const float go = acc[mt][nt][8 + a]  + bg[128 + c];
                const float gc = acc[mt][nt][12 + a] + bg[192 + c];
                const float ig = sigmoidf_(gi);
                const float fg = sigmoidf_(gf);
                const float og = sigmoidf_(go);
                const float cg = tanhf_(gc);
                const int idx = ((b * 64 + c) * 128 + yy) * 128 + px;
                const float cell = ig * cg + fg * pc[idx];
                const float hid  = og * tanhf_(cell);
                out[idx] = hid;
                out[NPIX_HID + idx] = cell;
            }
        }
    }
}

extern "C" void kernel_launch(void* const* d_in, const int* in_sizes, int n_in,
                              void* d_out, int out_size, void* d_ws, size_t ws_size,
                              hipStream_t stream) {
    const float* x  = (const float*)d_in[0];
    const float* ph = (const float*)d_in[1];
    const float* pc = (const float*)d_in[2];
    const float* W  = (const float*)d_in[3];
    const float* bg = (const float*)d_in[4];
    float* out = (float*)d_out;
    short* aprep = (short*)d_ws;   // 9*16*8*32*8 bf16 = 589,824 B

    wprep<<<1152, 256, 0, stream>>>(W, aprep);
    convlstm_main<<<1024, 256, 0, stream>>>(x, ph, pc, aprep, bg, out);
}